// Round 4
// baseline (272.453 us; speedup 1.0000x reference)
//
#include <hip/hip_runtime.h>

// Problem constants: B=16, T=64, N=128, D=512, H=512, O=256, A=18
#define TT 64
#define DD 512
#define HH 512
#define OO 256
#define AA 18
#define ROWS 1024

// ---------------------------------------------------------------------------
// K1: U = pathGCN1(obs @ W1). BM=64 rows == one batch (t = local row).
// 512 threads (8 waves -> 2 waves/SIMD), BN=32, BK=32, 2x2 micro-tile,
// double-buffered LDS: ONE barrier per K-tile, register prefetch.
// Grid: (512/32, 1024/64) = (16, 16) = 256 blocks.
// ---------------------------------------------------------------------------
__global__ __launch_bounds__(512) void k1_gemm_combine(
    const float* __restrict__ A, const float* __restrict__ W,
    const float* __restrict__ b1, float* __restrict__ U) {
  constexpr int BM = 64, BN = 32, BK = 32, NT = DD / BK;  // 16 tiles
  __shared__ float As[2][BK][BM + 4];  // transposed, stride 68 (16B mult)
  __shared__ float Bs[2][BK][BN + 8];  // stride 40 (16B mult)
  __shared__ float Gs[BM][BN + 4];     // stride 36 (16B mult)

  const int tid = threadIdx.x;
  const int tx = tid & 15, ty = tid >> 4;   // ty 0..31, tx 0..15
  const int col0 = blockIdx.x * BN;
  const int row0 = blockIdx.y * BM;
  const int ar = tid >> 3, ac = tid & 7;    // A: 1 float4/thread (64x32)
  const bool bload = tid < 256;             // B: 32x32 -> 256 float4

  float4 pa, pb;
  float acc00 = 0.f, acc01 = 0.f, acc10 = 0.f, acc11 = 0.f;

#define LOADG(kb)                                                              \
  {                                                                            \
    pa = *reinterpret_cast<const float4*>(                                     \
        &A[(size_t)(row0 + ar) * DD + (kb) + ac * 4]);                         \
    if (bload)                                                                 \
      pb = *reinterpret_cast<const float4*>(                                   \
          &W[(size_t)((kb) + ar) * HH + col0 + ac * 4]);                       \
  }

#define STOLDS(buf)                                                            \
  {                                                                            \
    As[buf][ac * 4 + 0][ar] = pa.x;                                            \
    As[buf][ac * 4 + 1][ar] = pa.y;                                            \
    As[buf][ac * 4 + 2][ar] = pa.z;                                            \
    As[buf][ac * 4 + 3][ar] = pa.w;                                            \
    if (bload) *reinterpret_cast<float4*>(&Bs[buf][ar][ac * 4]) = pb;          \
  }

#define COMPUTE(buf)                                                           \
  {                                                                            \
    _Pragma("unroll") for (int kk = 0; kk < BK; ++kk) {                        \
      const float2 av =                                                        \
          *reinterpret_cast<const float2*>(&As[buf][kk][ty * 2]);              \
      const float2 bv =                                                        \
          *reinterpret_cast<const float2*>(&Bs[buf][kk][tx * 2]);              \
      acc00 = fmaf(av.x, bv.x, acc00);                                         \
      acc01 = fmaf(av.x, bv.y, acc01);                                         \
      acc10 = fmaf(av.y, bv.x, acc10);                                         \
      acc11 = fmaf(av.y, bv.y, acc11);                                         \
    }                                                                          \
  }

  LOADG(0);
  STOLDS(0);
  __syncthreads();
#pragma unroll 4
  for (int t = 0; t < NT; ++t) {
    if (t + 1 < NT) LOADG((t + 1) * BK);
    COMPUTE(t & 1);
    if (t + 1 < NT) {
      STOLDS((t + 1) & 1);  // other buffer: safe while others still compute
      __syncthreads();
    }
  }
#undef LOADG
#undef STOLDS
#undef COMPUTE

  // Stage G tile for the cross-row combine.
  Gs[ty * 2 + 0][tx * 2 + 0] = acc00;
  Gs[ty * 2 + 0][tx * 2 + 1] = acc01;
  Gs[ty * 2 + 1][tx * 2 + 0] = acc10;
  Gs[ty * 2 + 1][tx * 2 + 1] = acc11;
  __syncthreads();

  // Combine: t == local row (tile is one batch). 64 rows x 8 col-groups.
  const int rr = tid >> 3;          // 0..63
  const int cg = (tid & 7) * 4;     // float4 col group
  const int t = rr;
  const float is6 = 0.4082482904638630f;  // 1/sqrt(6)
  float c0, c1, c2, d1, d2, al, be;
  if (t <= 1) {
    c0 = 0.f; c1 = 0.f; c2 = 1.f; d1 = 0.f; d2 = 0.f; al = 1.f; be = 0.f;
  } else if (t == 2) {
    c0 = 0.f; c1 = 0.5f; c2 = 0.5f; d1 = 0.5f; d2 = 0.5f; al = 0.5f; be = 0.5f;
  } else {
    c0 = (t == 3) ? is6 : (1.f / 3.f);
    c1 = 1.f / 3.f; c2 = is6;
    d1 = is6; d2 = 0.5f;
    al = is6; be = 0.5f;
  }
  const int rm1 = (rr >= 1) ? rr - 1 : 0;
  const int rm2 = (rr >= 2) ? rr - 2 : 0;

  const float4 gc = *reinterpret_cast<const float4*>(&Gs[rr][cg]);
  const float4 gb = *reinterpret_cast<const float4*>(&Gs[rm1][cg]);
  const float4 ga = *reinterpret_cast<const float4*>(&Gs[rm2][cg]);
  const float4 bb = *reinterpret_cast<const float4*>(&b1[col0 + cg]);

  float4 u;
#define ONE(fld)                                                               \
  {                                                                            \
    float h1a = fmaxf(c0 * ga.fld + c1 * gb.fld + c2 * gc.fld + bb.fld, 0.f);  \
    float h1b = fmaxf(d1 * gb.fld + d2 * gc.fld + bb.fld, 0.f);                \
    u.fld = al * h1a + be * h1b;                                               \
  }
  ONE(x) ONE(y) ONE(z) ONE(w)
#undef ONE
  *reinterpret_cast<float4*>(&U[(size_t)(row0 + rr) * HH + col0 + cg]) = u;
}

// ---------------------------------------------------------------------------
// K2: Tp[z] = U @ W2 partials, split-K=2. BM=32, BN=32, BK=32, 256 threads,
// 2x2 micro, double-buffered LDS (1 barrier/tile), register prefetch.
// Grid: (256/32, 1024/32, 2) = (8, 32, 2) = 512 blocks = 2 blocks/CU.
// ---------------------------------------------------------------------------
__global__ __launch_bounds__(256) void k2_gemm_sk(
    const float* __restrict__ A, const float* __restrict__ W,
    float* __restrict__ Tp) {
  constexpr int BM = 32, BN = 32, BK = 32, KC = HH / 2, NT = KC / BK;  // 8
  __shared__ float As[2][BK][BM + 4];  // stride 36
  __shared__ float Bs[2][BK][BN + 8];  // stride 40

  const int tid = threadIdx.x;
  const int tx = tid & 15, ty = tid >> 4;
  const int col0 = blockIdx.x * BN;
  const int row0 = blockIdx.y * BM;
  const int k0 = blockIdx.z * KC;
  const int ar = tid >> 3, ac = tid & 7;  // 1 float4/thread each side

  float4 pa, pb;
  float acc00 = 0.f, acc01 = 0.f, acc10 = 0.f, acc11 = 0.f;

#define LOADG(kb)                                                              \
  {                                                                            \
    pa = *reinterpret_cast<const float4*>(                                     \
        &A[(size_t)(row0 + ar) * HH + (kb) + ac * 4]);                         \
    pb = *reinterpret_cast<const float4*>(                                     \
        &W[(size_t)((kb) + ar) * OO + col0 + ac * 4]);                         \
  }

#define STOLDS(buf)                                                            \
  {                                                                            \
    As[buf][ac * 4 + 0][ar] = pa.x;                                            \
    As[buf][ac * 4 + 1][ar] = pa.y;                                            \
    As[buf][ac * 4 + 2][ar] = pa.z;                                            \
    As[buf][ac * 4 + 3][ar] = pa.w;                                            \
    *reinterpret_cast<float4*>(&Bs[buf][ar][ac * 4]) = pb;                     \
  }

#define COMPUTE(buf)                                                           \
  {                                                                            \
    _Pragma("unroll") for (int kk = 0; kk < BK; ++kk) {                        \
      const float2 av =                                                        \
          *reinterpret_cast<const float2*>(&As[buf][kk][ty * 2]);              \
      const float2 bv =                                                        \
          *reinterpret_cast<const float2*>(&Bs[buf][kk][tx * 2]);              \
      acc00 = fmaf(av.x, bv.x, acc00);                                         \
      acc01 = fmaf(av.x, bv.y, acc01);                                         \
      acc10 = fmaf(av.y, bv.x, acc10);                                         \
      acc11 = fmaf(av.y, bv.y, acc11);                                         \
    }                                                                          \
  }

  LOADG(k0);
  STOLDS(0);
  __syncthreads();
#pragma unroll 4
  for (int t = 0; t < NT; ++t) {
    if (t + 1 < NT) LOADG(k0 + (t + 1) * BK);
    COMPUTE(t & 1);
    if (t + 1 < NT) {
      STOLDS((t + 1) & 1);
      __syncthreads();
    }
  }
#undef LOADG
#undef STOLDS
#undef COMPUTE

  float* Pz = Tp + (size_t)blockIdx.z * ROWS * OO;
  const size_t o00 = (size_t)(row0 + ty * 2) * OO + col0 + tx * 2;
  *reinterpret_cast<float2*>(&Pz[o00]) = make_float2(acc00, acc01);
  *reinterpret_cast<float2*>(&Pz[o00 + OO]) = make_float2(acc10, acc11);
}

// ---------------------------------------------------------------------------
// K3: reduce 2 partials + b2 + relu -> tgt rows; out = tgt @ Wl + bl.
// 8 rows/block, grid 128.
// ---------------------------------------------------------------------------
__global__ __launch_bounds__(256) void k3_head(
    const float* __restrict__ Tp, const float* __restrict__ b2,
    const float* __restrict__ Wl, const float* __restrict__ bl,
    float* __restrict__ out) {
  __shared__ float sW[OO * AA];      // 18 KiB
  __shared__ float sT[8][OO + 8];

  constexpr size_t TSZ = (size_t)ROWS * OO;
  const int tid = threadIdx.x;
  for (int i = tid; i < OO * AA; i += 256) sW[i] = Wl[i];
  const int r0 = blockIdx.x * 8;
  for (int i = tid; i < 8 * OO; i += 256) {
    const int m = i >> 8, k = i & 255;
    const size_t g = (size_t)(r0 + m) * OO + k;
    sT[m][k] = fmaxf(Tp[g] + Tp[TSZ + g] + b2[k], 0.f);
  }
  __syncthreads();

  if (tid < 8 * AA) {
    const int m = tid / AA;
    const int o = tid - m * AA;
    float s = bl[o];
#pragma unroll 8
    for (int k = 0; k < OO; ++k) s = fmaf(sT[m][k], sW[k * AA + o], s);
    out[(size_t)(r0 + m) * AA + o] = s;
  }
}

extern "C" void kernel_launch(void* const* d_in, const int* in_sizes, int n_in,
                              void* d_out, int out_size, void* d_ws, size_t ws_size,
                              hipStream_t stream) {
  const float* obs = (const float*)d_in[0];   // [1024, 512]
  const float* W1 = (const float*)d_in[4];    // [512, 512]
  const float* b1 = (const float*)d_in[5];    // [512]
  const float* W2 = (const float*)d_in[6];    // [512, 256]
  const float* b2 = (const float*)d_in[7];    // [256]
  const float* Wl = (const float*)d_in[8];    // [256, 18]
  const float* bl = (const float*)d_in[9];    // [18]
  float* out = (float*)d_out;                 // [1024, 18]

  float* U  = (float*)d_ws;                   // 1024x512 = 2 MiB
  float* Tp = U + (size_t)ROWS * HH;          // 2 x 1024x256 = 2 MiB

  k1_gemm_combine<<<dim3(HH / 32, ROWS / 64), 512, 0, stream>>>(obs, W1, b1, U);
  k2_gemm_sk<<<dim3(OO / 32, ROWS / 32, 2), 256, 0, stream>>>(U, W2, Tp);
  k3_head<<<ROWS / 8, 256, 0, stream>>>(Tp, b2, Wl, bl, out);
}